// Round 1
// baseline (371.636 us; speedup 1.0000x reference)
//
#include <hip/hip_runtime.h>

typedef __attribute__((ext_vector_type(4))) float f32x4;
typedef __attribute__((ext_vector_type(8))) __bf16 bf16x8;
typedef __attribute__((ext_vector_type(4))) __bf16 bf16x4;

#define D_MODEL 1024
#define S_LEN 2048
#define MROWS 4096  // B*S

__device__ __forceinline__ void gload_lds16(const void* g, void* l) {
  __builtin_amdgcn_global_load_lds(
      (const __attribute__((address_space(1))) unsigned int*)g,
      (__attribute__((address_space(3))) unsigned int*)l, 16, 0, 0);
}

__global__ void cvt_f32_bf16(const float* __restrict__ in, __bf16* __restrict__ out, int n) {
  int i0 = (blockIdx.x * blockDim.x + threadIdx.x) * 4;
  int stride = gridDim.x * blockDim.x * 4;
  for (int i = i0; i < n; i += stride) {
    f32x4 v = *(const f32x4*)(in + i);
    bf16x4 o;
#pragma unroll
    for (int j = 0; j < 4; ++j) o[j] = (__bf16)v[j];
    *(bf16x4*)(out + i) = o;
  }
}

// C = A * B^T + bias.  A:[4096,1024] bf16 row-major, B:[1024,1024] bf16 row-major (W[n][k]).
// OUT=0: bf16 row-major [4096,1024]; OUT=1: bf16 transposed-V layout [(b*1024+n)*2048+s];
// OUT=2: f32 row-major.
template <int OUT>
__global__ __launch_bounds__(256) void gemm_bt(const __bf16* __restrict__ A,
                                               const __bf16* __restrict__ B,
                                               const float* __restrict__ bias,
                                               void* __restrict__ Cv) {
  __shared__ __bf16 As[128 * 32];
  __shared__ __bf16 Bs[128 * 32];
  const int tid = threadIdx.x;
  const int lane = tid & 63, wid = tid >> 6;
  const int li = lane & 15, g = lane >> 4;
  const int m0 = blockIdx.x * 128, n0 = blockIdx.y * 128;
  const int wr = wid >> 1, wc = wid & 1;
  const int srow = lane >> 2;        // staging row within a 16-row chunk
  const int scol = (lane & 3) * 8;   // staging col offset (elements)
  f32x4 acc[4][4] = {};
  for (int k0 = 0; k0 < D_MODEL; k0 += 32) {
#pragma unroll
    for (int i = 0; i < 2; ++i) {
      const int rb = (i * 4 + wid) * 16;
      gload_lds16(A + (size_t)(m0 + rb + srow) * D_MODEL + k0 + scol, &As[rb * 32]);
      gload_lds16(B + (size_t)(n0 + rb + srow) * D_MODEL + k0 + scol, &Bs[rb * 32]);
    }
    __syncthreads();
    bf16x8 af[4], bfr[4];
#pragma unroll
    for (int i = 0; i < 4; ++i) {
      af[i]  = *(const bf16x8*)&As[(wr * 64 + i * 16 + li) * 32 + g * 8];
      bfr[i] = *(const bf16x8*)&Bs[(wc * 64 + i * 16 + li) * 32 + g * 8];
    }
#pragma unroll
    for (int i = 0; i < 4; ++i)
#pragma unroll
      for (int j = 0; j < 4; ++j)
        acc[i][j] = __builtin_amdgcn_mfma_f32_16x16x32_bf16(af[i], bfr[j], acc[i][j], 0, 0, 0);
    __syncthreads();
  }
#pragma unroll
  for (int j = 0; j < 4; ++j) {
    const int n = n0 + wc * 64 + j * 16 + li;
    const float bv = bias[n];
#pragma unroll
    for (int i = 0; i < 4; ++i) {
#pragma unroll
      for (int r = 0; r < 4; ++r) {
        const int m = m0 + wr * 64 + i * 16 + g * 4 + r;
        const float v = acc[i][j][r] + bv;
        if (OUT == 0) {
          ((__bf16*)Cv)[(size_t)m * D_MODEL + n] = (__bf16)v;
        } else if (OUT == 1) {
          const int bb = m >> 11, s = m & 2047;
          ((__bf16*)Cv)[((size_t)(bb * D_MODEL + n)) * S_LEN + s] = (__bf16)v;
        } else {
          ((float*)Cv)[(size_t)m * D_MODEL + n] = v;
        }
      }
    }
  }
}

// Fused causal attention. qp/kp: [B*S,1024] bf16 (heads in columns). vt: [B*H*64, S] bf16.
// Writes attn (f32, [B,H,S,S]) and ctx ([B*S,1024] bf16).
__global__ __launch_bounds__(256) void attn_fused(const __bf16* __restrict__ qp,
                                                  const __bf16* __restrict__ kp,
                                                  const __bf16* __restrict__ vt,
                                                  float* __restrict__ attn,
                                                  __bf16* __restrict__ ctx) {
  const int bh = blockIdx.x;  // b*16+h
  const int qt = blockIdx.y;  // q-tile of 64 rows
  const int b = bh >> 4, h = bh & 15;
  const int tid = threadIdx.x, lane = tid & 63, wid = tid >> 6;
  const int li = lane & 15, g = lane >> 4;
  const int qrow0 = qt * 64 + wid * 16;
  const float NEG_INF = -__builtin_inff();

  __shared__ __bf16 k_lds[32 * 64];
  __shared__ __bf16 vt_lds[64 * 32];
  __shared__ __bf16 p_lds[4][16 * 32];

  const __bf16* qbase = qp + ((size_t)(b * S_LEN) + qrow0 + li) * D_MODEL + h * 64 + g * 8;
  const bf16x8 qf0 = *(const bf16x8*)qbase;
  const bf16x8 qf1 = *(const bf16x8*)(qbase + 32);

  const int NKT = 2 * qt + 2;
  float m[4], l[4];
#pragma unroll
  for (int r = 0; r < 4; ++r) { m[r] = NEG_INF; l[r] = 0.f; }

  const int krow = wid * 8 + (lane >> 3);
  const int kchunk = (lane & 7) * 8;

  // Pass 1: online row max & sum
  for (int kt = 0; kt < NKT; ++kt) {
    gload_lds16(kp + ((size_t)(b * S_LEN) + kt * 32 + krow) * D_MODEL + h * 64 + kchunk,
                &k_lds[wid * 8 * 64]);
    __syncthreads();
#pragma unroll
    for (int sub = 0; sub < 2; ++sub) {
      const bf16x8 kf0 = *(const bf16x8*)&k_lds[(sub * 16 + li) * 64 + g * 8];
      const bf16x8 kf1 = *(const bf16x8*)&k_lds[(sub * 16 + li) * 64 + 32 + g * 8];
      f32x4 s = {};
      s = __builtin_amdgcn_mfma_f32_16x16x32_bf16(qf0, kf0, s, 0, 0, 0);
      s = __builtin_amdgcn_mfma_f32_16x16x32_bf16(qf1, kf1, s, 0, 0, 0);
      const int col = kt * 32 + sub * 16 + li;
#pragma unroll
      for (int r = 0; r < 4; ++r) {
        const int row = qrow0 + g * 4 + r;
        const float sv = (col <= row) ? s[r] * 0.125f : NEG_INF;
        float tm = sv;
        tm = fmaxf(tm, __shfl_xor(tm, 1));
        tm = fmaxf(tm, __shfl_xor(tm, 2));
        tm = fmaxf(tm, __shfl_xor(tm, 4));
        tm = fmaxf(tm, __shfl_xor(tm, 8));
        const float mn = fmaxf(m[r], tm);
        float ts = __expf(sv - mn);  // exp(-inf)=0 for masked
        ts += __shfl_xor(ts, 1);
        ts += __shfl_xor(ts, 2);
        ts += __shfl_xor(ts, 4);
        ts += __shfl_xor(ts, 8);
        l[r] = l[r] * __expf(m[r] - mn) + ts;
        m[r] = mn;
      }
    }
    __syncthreads();
  }

  float inv_l[4];
#pragma unroll
  for (int r = 0; r < 4; ++r) inv_l[r] = 1.f / l[r];

  float* attn_bh = attn + (size_t)bh * S_LEN * S_LEN;
  f32x4 acc[4] = {};

  const int vrow = wid * 16 + (lane >> 2);
  const int vchunk = (lane & 3) * 8;

  // Pass 2: recompute scores, write attn, accumulate PV
  for (int kt = 0; kt < NKT; ++kt) {
    gload_lds16(kp + ((size_t)(b * S_LEN) + kt * 32 + krow) * D_MODEL + h * 64 + kchunk,
                &k_lds[wid * 8 * 64]);
    gload_lds16(vt + ((size_t)(bh * 64) + vrow) * S_LEN + kt * 32 + vchunk,
                &vt_lds[wid * 16 * 32]);
    __syncthreads();
#pragma unroll
    for (int sub = 0; sub < 2; ++sub) {
      const bf16x8 kf0 = *(const bf16x8*)&k_lds[(sub * 16 + li) * 64 + g * 8];
      const bf16x8 kf1 = *(const bf16x8*)&k_lds[(sub * 16 + li) * 64 + 32 + g * 8];
      f32x4 s = {};
      s = __builtin_amdgcn_mfma_f32_16x16x32_bf16(qf0, kf0, s, 0, 0, 0);
      s = __builtin_amdgcn_mfma_f32_16x16x32_bf16(qf1, kf1, s, 0, 0, 0);
      const int col = kt * 32 + sub * 16 + li;
#pragma unroll
      for (int r = 0; r < 4; ++r) {
        const int row = qrow0 + g * 4 + r;
        const float sv = (col <= row) ? s[r] * 0.125f : NEG_INF;
        const float p = __expf(sv - m[r]) * inv_l[r];
        attn_bh[(size_t)row * S_LEN + col] = p;
        p_lds[wid][(g * 4 + r) * 32 + sub * 16 + li] = (__bf16)p;
      }
    }
    __syncthreads();
    const bf16x8 pa = *(const bf16x8*)&p_lds[wid][li * 32 + g * 8];
#pragma unroll
    for (int c = 0; c < 4; ++c) {
      const bf16x8 vf = *(const bf16x8*)&vt_lds[(c * 16 + li) * 32 + g * 8];
      acc[c] = __builtin_amdgcn_mfma_f32_16x16x32_bf16(pa, vf, acc[c], 0, 0, 0);
    }
    __syncthreads();
  }

  // ctx write (merge heads: feature = h*64 + d)
#pragma unroll
  for (int c = 0; c < 4; ++c)
#pragma unroll
    for (int r = 0; r < 4; ++r)
      ctx[((size_t)(b * S_LEN) + qrow0 + g * 4 + r) * D_MODEL + h * 64 + c * 16 + li] =
          (__bf16)acc[c][r];

  // zero the masked tail of attn rows
  const int c0 = NKT * 32;
  for (int r = 0; r < 16; ++r) {
    float* rowp = attn_bh + (size_t)(qrow0 + r) * S_LEN;
    for (int col = c0 + lane * 4; col < S_LEN; col += 256) {
      f32x4 z = {};
      *(f32x4*)(rowp + col) = z;
    }
  }
}

extern "C" void kernel_launch(void* const* d_in, const int* in_sizes, int n_in,
                              void* d_out, int out_size, void* d_ws, size_t ws_size,
                              hipStream_t stream) {
  const float* Q  = (const float*)d_in[0];
  const float* K  = (const float*)d_in[1];
  const float* V  = (const float*)d_in[2];
  const float* W_Q = (const float*)d_in[4];
  const float* b_Q = (const float*)d_in[5];
  const float* W_K = (const float*)d_in[6];
  const float* b_K = (const float*)d_in[7];
  const float* W_V = (const float*)d_in[8];
  const float* b_V = (const float*)d_in[9];
  const float* W_O = (const float*)d_in[10];
  const float* b_O = (const float*)d_in[11];

  char* ws = (char*)d_ws;
  __bf16* Qb  = (__bf16*)(ws + 0);
  __bf16* Kb  = (__bf16*)(ws + 8388608);
  __bf16* Vb  = (__bf16*)(ws + 16777216);
  __bf16* Wq  = (__bf16*)(ws + 25165824);
  __bf16* Wk  = (__bf16*)(ws + 27262976);
  __bf16* Wv  = (__bf16*)(ws + 29360128);
  __bf16* Wo  = (__bf16*)(ws + 31457280);
  __bf16* qp  = (__bf16*)(ws + 33554432);
  __bf16* kp  = (__bf16*)(ws + 41943040);
  __bf16* vtb = (__bf16*)(ws + 50331648);
  __bf16* ctx = (__bf16*)(ws + 58720256);  // end: 64 MiB

  float* out = (float*)d_out;
  float* attn = out + (size_t)MROWS * D_MODEL;  // out first, then attn

  cvt_f32_bf16<<<2048, 256, 0, stream>>>(Q, Qb, MROWS * D_MODEL);
  cvt_f32_bf16<<<2048, 256, 0, stream>>>(K, Kb, MROWS * D_MODEL);
  cvt_f32_bf16<<<2048, 256, 0, stream>>>(V, Vb, MROWS * D_MODEL);
  cvt_f32_bf16<<<1024, 256, 0, stream>>>(W_Q, Wq, D_MODEL * D_MODEL);
  cvt_f32_bf16<<<1024, 256, 0, stream>>>(W_K, Wk, D_MODEL * D_MODEL);
  cvt_f32_bf16<<<1024, 256, 0, stream>>>(W_V, Wv, D_MODEL * D_MODEL);
  cvt_f32_bf16<<<1024, 256, 0, stream>>>(W_O, Wo, D_MODEL * D_MODEL);

  dim3 gg(MROWS / 128, D_MODEL / 128);
  gemm_bt<0><<<gg, 256, 0, stream>>>(Qb, Wq, b_Q, qp);
  gemm_bt<0><<<gg, 256, 0, stream>>>(Kb, Wk, b_K, kp);
  gemm_bt<1><<<gg, 256, 0, stream>>>(Vb, Wv, b_V, vtb);

  dim3 ga(32, S_LEN / 64);
  attn_fused<<<ga, 256, 0, stream>>>(qp, kp, vtb, attn, ctx);

  gemm_bt<2><<<gg, 256, 0, stream>>>(ctx, Wo, b_O, d_out);
}

// Round 2
// 247.574 us; speedup vs baseline: 1.5011x; 1.5011x over previous
//
#include <hip/hip_runtime.h>

typedef __attribute__((ext_vector_type(4))) float f32x4;
typedef __attribute__((ext_vector_type(8))) __bf16 bf16x8;
typedef __attribute__((ext_vector_type(4))) __bf16 bf16x4;

#define D_MODEL 1024
#define S_LEN 2048
#define MROWS 4096  // B*S

#if __has_builtin(__builtin_amdgcn_exp2f)
#define EXP2F(x) __builtin_amdgcn_exp2f(x)
#else
#define EXP2F(x) exp2f(x)
#endif
#if __has_builtin(__builtin_amdgcn_logf)
#define LOG2F(x) __builtin_amdgcn_logf(x)
#else
#define LOG2F(x) log2f(x)
#endif

// 0.125 (1/sqrt(d_k)) * log2(e): folded into W_Q/b_Q so scores are in exp2 domain.
#define QSCALE 0.1803368801111204f

__device__ __forceinline__ void gload_lds16(const void* g, void* l) {
  __builtin_amdgcn_global_load_lds(
      (const __attribute__((address_space(1))) unsigned int*)g,
      (__attribute__((address_space(3))) unsigned int*)l, 16, 0, 0);
}

// ---- conversions ----
__global__ void cvt_qkv(const float* __restrict__ Q, const float* __restrict__ K,
                        const float* __restrict__ V, __bf16* __restrict__ dst) {
  const int y = blockIdx.y;
  const float* src = (y == 0) ? Q : (y == 1) ? K : V;
  __bf16* d = dst + (size_t)y * (MROWS * D_MODEL);
  const int n4 = MROWS * D_MODEL / 4;
  for (int i = blockIdx.x * blockDim.x + threadIdx.x; i < n4; i += 512 * 256) {
    f32x4 v = *(const f32x4*)(src + i * 4);
    bf16x4 o;
#pragma unroll
    for (int j = 0; j < 4; ++j) o[j] = (__bf16)v[j];
    *(bf16x4*)(d + i * 4) = o;
  }
}

__global__ void cvt_w(const float* __restrict__ w0, const float* __restrict__ w1,
                      const float* __restrict__ w2, const float* __restrict__ w3,
                      __bf16* __restrict__ dst) {
  const int y = blockIdx.y;
  const float* src = (y == 0) ? w0 : (y == 1) ? w1 : (y == 2) ? w2 : w3;
  const float sc = (y == 0) ? QSCALE : 1.0f;
  __bf16* d = dst + (size_t)y * (D_MODEL * D_MODEL);
  const int n4 = D_MODEL * D_MODEL / 4;
  for (int i = blockIdx.x * blockDim.x + threadIdx.x; i < n4; i += 256 * 256) {
    f32x4 v = *(const f32x4*)(src + i * 4);
    bf16x4 o;
#pragma unroll
    for (int j = 0; j < 4; ++j) o[j] = (__bf16)(v[j] * sc);
    *(bf16x4*)(d + i * 4) = o;
  }
}

// ---- GEMM core: 128x128 tile, BK=64, XOR-swizzled LDS (chunk ^= row&7) ----
__device__ __forceinline__ void gemm_core64(const __bf16* __restrict__ A,
                                            const __bf16* __restrict__ B,
                                            __bf16* As, __bf16* Bs,
                                            int m0, int n0, f32x4 (&acc)[4][4]) {
  const int tid = threadIdx.x;
  const int lane = tid & 63, wid = tid >> 6;
  const int li = lane & 15, g = lane >> 4;
  const int wr = wid >> 1, wc = wid & 1;
  const int srow = tid >> 3, sc = tid & 7;
  const int scol = (sc ^ (srow & 7)) * 8;  // pre-swizzled global chunk (rule #21)
  const int sw = li & 7;
  for (int k0 = 0; k0 < D_MODEL; k0 += 64) {
#pragma unroll
    for (int i = 0; i < 4; ++i) {
      const int r = i * 32 + srow;
      gload_lds16(A + (size_t)(m0 + r) * D_MODEL + k0 + scol, (char*)As + i * 4096 + wid * 1024);
      gload_lds16(B + (size_t)(n0 + r) * D_MODEL + k0 + scol, (char*)Bs + i * 4096 + wid * 1024);
    }
    __syncthreads();
#pragma unroll
    for (int kk = 0; kk < 2; ++kk) {
      bf16x8 af[4], bfr[4];
#pragma unroll
      for (int i = 0; i < 4; ++i) {
        af[i]  = *(const bf16x8*)&As[(wr * 64 + i * 16 + li) * 64 + (((kk * 4 + g) ^ sw) * 8)];
        bfr[i] = *(const bf16x8*)&Bs[(wc * 64 + i * 16 + li) * 64 + (((kk * 4 + g) ^ sw) * 8)];
      }
      __builtin_amdgcn_s_setprio(1);
#pragma unroll
      for (int i = 0; i < 4; ++i)
#pragma unroll
        for (int j = 0; j < 4; ++j)
          acc[i][j] = __builtin_amdgcn_mfma_f32_16x16x32_bf16(af[i], bfr[j], acc[i][j], 0, 0, 0);
      __builtin_amdgcn_s_setprio(0);
    }
    __syncthreads();
  }
}

// Fused Q/K/V projection: grid (32, 8, 3). z=2 writes V transposed [(b*1024+n)*2048+s].
__global__ __launch_bounds__(256) void qkv_gemm(
    const __bf16* __restrict__ Qb, const __bf16* __restrict__ Kb, const __bf16* __restrict__ Vb,
    const __bf16* __restrict__ Wq, const __bf16* __restrict__ Wk, const __bf16* __restrict__ Wv,
    const float* __restrict__ bq, const float* __restrict__ bk, const float* __restrict__ bv,
    __bf16* __restrict__ qp, __bf16* __restrict__ kp, __bf16* __restrict__ vt) {
  __shared__ __bf16 As[128 * 64];
  __shared__ __bf16 Bs[128 * 64];
  const int z = blockIdx.z;
  const __bf16* A = (z == 0) ? Qb : (z == 1) ? Kb : Vb;
  const __bf16* B = (z == 0) ? Wq : (z == 1) ? Wk : Wv;
  const float* bias = (z == 0) ? bq : (z == 1) ? bk : bv;
  const float bsc = (z == 0) ? QSCALE : 1.0f;
  const int m0 = blockIdx.x * 128, n0 = blockIdx.y * 128;
  f32x4 acc[4][4] = {};
  gemm_core64(A, B, As, Bs, m0, n0, acc);

  const int lane = threadIdx.x & 63, wid = threadIdx.x >> 6;
  const int li = lane & 15, g = lane >> 4;
  const int wr = wid >> 1, wc = wid & 1;
#pragma unroll
  for (int j = 0; j < 4; ++j) {
    const int n = n0 + wc * 64 + j * 16 + li;
    const float bv_ = bias[n] * bsc;
#pragma unroll
    for (int i = 0; i < 4; ++i) {
#pragma unroll
      for (int r = 0; r < 4; ++r) {
        const int m = m0 + wr * 64 + i * 16 + g * 4 + r;
        const float v = acc[i][j][r] + bv_;
        if (z == 2) {
          const int bb = m >> 11, s = m & 2047;
          vt[((size_t)(bb * D_MODEL + n)) * S_LEN + s] = (__bf16)v;
        } else {
          __bf16* o = (z == 0) ? qp : kp;
          o[(size_t)m * D_MODEL + n] = (__bf16)v;
        }
      }
    }
  }
}

__global__ __launch_bounds__(256) void o_gemm(const __bf16* __restrict__ ctx,
                                              const __bf16* __restrict__ Wo,
                                              const float* __restrict__ bo,
                                              float* __restrict__ out) {
  __shared__ __bf16 As[128 * 64];
  __shared__ __bf16 Bs[128 * 64];
  const int m0 = blockIdx.x * 128, n0 = blockIdx.y * 128;
  f32x4 acc[4][4] = {};
  gemm_core64(ctx, Wo, As, Bs, m0, n0, acc);

  const int lane = threadIdx.x & 63, wid = threadIdx.x >> 6;
  const int li = lane & 15, g = lane >> 4;
  const int wr = wid >> 1, wc = wid & 1;
#pragma unroll
  for (int j = 0; j < 4; ++j) {
    const int n = n0 + wc * 64 + j * 16 + li;
    const float bv_ = bo[n];
#pragma unroll
    for (int i = 0; i < 4; ++i)
#pragma unroll
      for (int r = 0; r < 4; ++r) {
        const int m = m0 + wr * 64 + i * 16 + g * 4 + r;
        out[(size_t)m * D_MODEL + n] = acc[i][j][r] + bv_;
      }
  }
}

// ---- Fused causal attention, 64-wide KV tiles, exp2-domain softmax ----
// qp pre-scaled by 0.125*log2e. kp: [B*S,1024]. vt: [(b*1024+h*64+d)*2048+s].
__global__ __launch_bounds__(256) void attn_fused2(const __bf16* __restrict__ qp,
                                                   const __bf16* __restrict__ kp,
                                                   const __bf16* __restrict__ vt,
                                                   float* __restrict__ attn,
                                                   __bf16* __restrict__ ctx) {
  const int bid = blockIdx.x;
  const int qt = 31 - (bid >> 5);  // longest-first
  const int bh = bid & 31;
  const int b = bh >> 4, h = bh & 15;
  const int tid = threadIdx.x, lane = tid & 63, wid = tid >> 6;
  const int li = lane & 15, g = lane >> 4;
  const int sw = li & 7;
  const int qrow0 = qt * 64 + wid * 16;
  const float NEG_INF = -__builtin_inff();

  __shared__ __bf16 k_lds[2][64 * 64];
  __shared__ __bf16 v_lds[2][64 * 64];
  __shared__ __bf16 p_lds[4][16 * 64];

  // Q fragments (A-operand: lane row = li, d-chunk = g*8)
  const __bf16* qbase = qp + ((size_t)(b * S_LEN + qrow0 + li)) * D_MODEL + h * 64 + g * 8;
  const bf16x8 qf0 = *(const bf16x8*)qbase;
  const bf16x8 qf1 = *(const bf16x8*)(qbase + 32);

  // staging map (swizzled source chunk; LDS dest linear — rule #21)
  const int srow = tid >> 3;
  const int sc = tid & 7;
  const int schunk = (sc ^ (srow & 7)) * 8;
  const __bf16* kpb = kp + (size_t)(b * S_LEN) * D_MODEL + h * 64 + schunk;
  const __bf16* vpb = vt + (size_t)(bh * 64) * S_LEN + schunk;

  auto stage_k = [&](int kt, int bufi) {
#pragma unroll
    for (int i = 0; i < 2; ++i)
      gload_lds16(kpb + (size_t)(kt * 64 + i * 32 + srow) * D_MODEL,
                  (char*)k_lds[bufi] + i * 4096 + wid * 1024);
  };
  auto stage_v = [&](int kt, int bufi) {
#pragma unroll
    for (int i = 0; i < 2; ++i)
      gload_lds16(vpb + (size_t)(i * 32 + srow) * S_LEN + kt * 64,
                  (char*)v_lds[bufi] + i * 4096 + wid * 1024);
  };
  auto qk_tile = [&](const __bf16* kb, f32x4 (&sv)[4]) {
    __builtin_amdgcn_s_setprio(1);
#pragma unroll
    for (int sub = 0; sub < 4; ++sub) {
      const __bf16* rp = kb + (sub * 16 + li) * 64;
      const bf16x8 k0 = *(const bf16x8*)(rp + ((g ^ sw) * 8));
      const bf16x8 k1 = *(const bf16x8*)(rp + (((4 + g) ^ sw) * 8));
      f32x4 t = {};
      t = __builtin_amdgcn_mfma_f32_16x16x32_bf16(qf0, k0, t, 0, 0, 0);
      t = __builtin_amdgcn_mfma_f32_16x16x32_bf16(qf1, k1, t, 0, 0, 0);
      sv[sub] = t;
    }
    __builtin_amdgcn_s_setprio(0);
  };

  // ---- Pass 1: row max + denominator (exp2 domain) ----
  float m_[4], l_[4];
#pragma unroll
  for (int r = 0; r < 4; ++r) { m_[r] = NEG_INF; l_[r] = 0.f; }

  int buf = 0;
  stage_k(0, 0);
  for (int kt = 0; kt <= qt; ++kt) {
    __syncthreads();
    stage_k(kt + 1, buf ^ 1);  // prefetch (last one reads scratch ws — harmless)
    f32x4 sv[4];
    qk_tile(k_lds[buf], sv);
    if (kt == qt) {  // diagonal tile: per-element causal mask (uniform branch)
      const int rowl = wid * 16 + g * 4;
#pragma unroll
      for (int sub = 0; sub < 4; ++sub) {
        const int coll = sub * 16 + li;
#pragma unroll
        for (int r = 0; r < 4; ++r)
          if (coll > rowl + r) sv[sub][r] = NEG_INF;
      }
    }
#pragma unroll
    for (int r = 0; r < 4; ++r) {
      const float v0 = sv[0][r], v1 = sv[1][r], v2 = sv[2][r], v3 = sv[3][r];
      float tm = fmaxf(fmaxf(v0, v1), fmaxf(v2, v3));
      tm = fmaxf(tm, __shfl_xor(tm, 1));
      tm = fmaxf(tm, __shfl_xor(tm, 2));
      tm = fmaxf(tm, __shfl_xor(tm, 4));
      tm = fmaxf(tm, __shfl_xor(tm, 8));
      const float mn = fmaxf(m_[r], tm);
      float e = (EXP2F(v0 - mn) + EXP2F(v1 - mn)) + (EXP2F(v2 - mn) + EXP2F(v3 - mn));
      e += __shfl_xor(e, 1);
      e += __shfl_xor(e, 2);
      e += __shfl_xor(e, 4);
      e += __shfl_xor(e, 8);
      l_[r] = l_[r] * EXP2F(m_[r] - mn) + e;
      m_[r] = mn;
    }
    buf ^= 1;
  }

  // ---- Pass 2: p = exp2(s - (m + log2 l)); write attn f32; PV accumulate ----
  float c_[4];
#pragma unroll
  for (int r = 0; r < 4; ++r) c_[r] = m_[r] + LOG2F(l_[r]);

  float* attn_bh = attn + (size_t)bh * S_LEN * S_LEN;
  float* arp[4];
#pragma unroll
  for (int r = 0; r < 4; ++r)
    arp[r] = attn_bh + (size_t)(qrow0 + g * 4 + r) * S_LEN + li;

  __bf16* pw = &p_lds[wid][0];
  f32x4 acc[4] = {};

  __syncthreads();  // all pass-1 reads done before restaging buf0
  buf = 0;
  stage_k(0, 0);
  stage_v(0, 0);
  for (int kt = 0; kt <= qt; ++kt) {
    __syncthreads();
    stage_k(kt + 1, buf ^ 1);
    stage_v(kt + 1, buf ^ 1);
    f32x4 sv[4];
    qk_tile(k_lds[buf], sv);
    if (kt == qt) {
      const int rowl = wid * 16 + g * 4;
#pragma unroll
      for (int sub = 0; sub < 4; ++sub) {
        const int coll = sub * 16 + li;
#pragma unroll
        for (int r = 0; r < 4; ++r)
          if (coll > rowl + r) sv[sub][r] = NEG_INF;
      }
    }
    const int colbase = kt * 64;
#pragma unroll
    for (int r = 0; r < 4; ++r) {
      const int prow = g * 4 + r;
#pragma unroll
      for (int sub = 0; sub < 4; ++sub) {
        const float p = EXP2F(sv[sub][r] - c_[r]);
        arp[r][colbase + sub * 16] = p;
        // swizzled p_lds write (chunk ^= row&7), per-wave private region
        pw[prow * 64 + (((sub * 2 + (li >> 3)) ^ (prow & 7)) * 8) + (li & 7)] = (__bf16)p;
      }
    }
    // PV (p_lds write->read same wave: compiler inserts lgkmcnt wait)
    __builtin_amdgcn_s_setprio(1);
    const bf16x8 pa0 = *(const bf16x8*)&pw[li * 64 + ((g ^ sw) * 8)];
    const bf16x8 pa1 = *(const bf16x8*)&pw[li * 64 + (((4 + g) ^ sw) * 8)];
    const __bf16* vb = v_lds[buf];
#pragma unroll
    for (int c4 = 0; c4 < 4; ++c4) {
      const __bf16* vrp = vb + (c4 * 16 + li) * 64;
      const bf16x8 vf0 = *(const bf16x8*)(vrp + ((g ^ sw) * 8));
      const bf16x8 vf1 = *(const bf16x8*)(vrp + (((4 + g) ^ sw) * 8));
      acc[c4] = __builtin_amdgcn_mfma_f32_16x16x32_bf16(pa0, vf0, acc[c4], 0, 0, 0);
      acc[c4] = __builtin_amdgcn_mfma_f32_16x16x32_bf16(pa1, vf1, acc[c4], 0, 0, 0);
    }
    __builtin_amdgcn_s_setprio(0);
    buf ^= 1;
  }

  // ctx write (merge heads)
#pragma unroll
  for (int c4 = 0; c4 < 4; ++c4)
#pragma unroll
    for (int r = 0; r < 4; ++r)
      ctx[((size_t)(b * S_LEN) + qrow0 + g * 4 + r) * D_MODEL + h * 64 + c4 * 16 + li] =
          (__bf16)acc[c4][r];

  // zero the causal upper-triangle tail
  const int c0 = (qt + 1) * 64;
  for (int r = 0; r < 16; ++r) {
    float* rowp = attn_bh + (size_t)(qrow0 + r) * S_LEN;
    for (int col = c0 + lane * 4; col < S_LEN; col += 256) {
      f32x4 z = {};
      *(f32x4*)(rowp + col) = z;
    }
  }
}

extern "C" void kernel_launch(void* const* d_in, const int* in_sizes, int n_in,
                              void* d_out, int out_size, void* d_ws, size_t ws_size,
                              hipStream_t stream) {
  const float* Q  = (const float*)d_in[0];
  const float* K  = (const float*)d_in[1];
  const float* V  = (const float*)d_in[2];
  const float* W_Q = (const float*)d_in[4];
  const float* b_Q = (const float*)d_in[5];
  const float* W_K = (const float*)d_in[6];
  const float* b_K = (const float*)d_in[7];
  const float* W_V = (const float*)d_in[8];
  const float* b_V = (const float*)d_in[9];
  const float* W_O = (const float*)d_in[10];
  const float* b_O = (const float*)d_in[11];

  char* ws = (char*)d_ws;
  __bf16* Qb  = (__bf16*)(ws + 0);          // 3 x 8.39MB (contiguous for cvt_qkv)
  __bf16* Wq  = (__bf16*)(ws + 25165824);   // 4 x 2MB (contiguous for cvt_w)
  __bf16* qp  = (__bf16*)(ws + 33554432);
  __bf16* kp  = (__bf16*)(ws + 41943040);
  __bf16* vtb = (__bf16*)(ws + 50331648);
  __bf16* ctx = (__bf16*)(ws + 58720256);   // end: 64 MiB
  __bf16* Kb = Qb + (size_t)MROWS * D_MODEL;
  __bf16* Vb = Kb + (size_t)MROWS * D_MODEL;
  __bf16* Wk = Wq + (size_t)D_MODEL * D_MODEL;
  __bf16* Wv = Wk + (size_t)D_MODEL * D_MODEL;
  __bf16* Wo = Wv + (size_t)D_MODEL * D_MODEL;

  float* out = (float*)d_out;
  float* attn = out + (size_t)MROWS * D_MODEL;

  cvt_qkv<<<dim3(512, 3), 256, 0, stream>>>(Q, K, V, Qb);
  cvt_w<<<dim3(256, 4), 256, 0, stream>>>(W_Q, W_K, W_V, W_O, Wq);

  qkv_gemm<<<dim3(32, 8, 3), 256, 0, stream>>>(Qb, Kb, Vb, Wq, Wk, Wv,
                                               b_Q, b_K, b_V, qp, kp, vtb);

  attn_fused2<<<1024, 256, 0, stream>>>(qp, kp, vtb, attn, ctx);

  o_gemm<<<dim3(32, 8), 256, 0, stream>>>(ctx, Wo, b_O, out);
}